// Round 4
// baseline (332.364 us; speedup 1.0000x reference)
//
#include <hip/hip_runtime.h>
#include <stdint.h>

#define TOKENS 8192
#define INF    4096
#define OUTF   4096
#define RANK   256

typedef __attribute__((ext_vector_type(8))) short bf16x8;
typedef __attribute__((ext_vector_type(4))) float f32x4;

__device__ __forceinline__ unsigned short f2bf(float f) {
    union { float f; unsigned int u; } v; v.f = f;
    unsigned int r = v.u + 0x7FFFu + ((v.u >> 16) & 1u);   // RNE
    return (unsigned short)(r >> 16);
}

__device__ __forceinline__ void gl_lds16(const void* g, void* l) {
    __builtin_amdgcn_global_load_lds(
        (const __attribute__((address_space(1))) unsigned int*)g,
        (__attribute__((address_space(3))) unsigned int*)l, 16, 0, 0);
}

// ---------------- fp32 -> bf16 convert (V then U, one launch) ----------------
__global__ void cvt4(const float4* __restrict__ va, ushort4* __restrict__ oa, int na,
                     const float4* __restrict__ vb, ushort4* __restrict__ ob) {
    int i = blockIdx.x * blockDim.x + threadIdx.x;
    float4 v;
    if (i < na) v = va[i]; else v = vb[i - na];
    ushort4 o;
    o.x = f2bf(v.x); o.y = f2bf(v.y); o.z = f2bf(v.z); o.w = f2bf(v.w);
    if (i < na) oa[i] = o; else ob[i - na] = o;
}

// ---------------- fused: out = (x @ V^T) @ U^T + bias ----------------
// 256 blocks x 512 thr (8 waves), 1 block/CU. BM=32 tokens per block.
// Phase 1 (proven round-3 gemm1 structure): T[32,256] = x_blk @ V^T,
//   BK=128, V via global_load_lds (un-sinkable DMA) double-buffered 2x64KB,
//   x via fp32 load -> bf16 pack -> ds_write, 2-tiles-ahead register pipeline.
// Transition: acc -> bf16 -> LDS T (XOR-swizzled 16B chunks), then T -> 16
//   bf16x8 registers per wave (loop-invariant for phase 2).
// Phase 2: out_blk[32,4096] = T @ U^T + bias, 32 iters of 128-outf U tiles,
//   double-buffered in the same 2x64KB LDS, one barrier per tile,
//   16 MFMA : 8 ds_read per wave per tile. No T round-trip via HBM, no
//   device-wide sync between the two gemms.
#define BM   32
#define BK   128
#define ASTR 136                 // x-tile row stride (128+8 pad)

// shared layout (ushort units); total 74240 shorts = 145 KB
#define VB0 0
#define VB1 32768
#define AB0 65536
#define AB1 (65536 + 4352)
#define TB0 65536                // T[32][256] overlays A0+A1 (8192 shorts)
#define SMSZ 74240

__device__ __forceinline__ void stageV(const unsigned short* __restrict__ Vb,
                                       unsigned short* vdst, int kk,
                                       int wid, int lane) {
    // linear dest + inverse-swizzled source; read side XORs the same way
    #pragma unroll
    for (int j = 0; j < 8; ++j) {
        int r0  = wid * 32 + j * 4;
        int row = r0 + (lane >> 4);
        int c   = (lane & 15) ^ (row & 7);
        gl_lds16(Vb + (size_t)row * INF + kk + c * 8, vdst + r0 * BK);
    }
}

__device__ __forceinline__ void stageU(const unsigned short* __restrict__ Ub,
                                       unsigned short* udst, int nb,
                                       int wid, int lane) {
    // tile = 128 outf rows x 256 rank (64 KB); wave stages its own 16 rows
    int rp = lane >> 5;          // row parity within call (2 rows/call)
    int c  = lane & 31;          // 16B chunk within row (32 chunks)
    #pragma unroll
    for (int j = 0; j < 8; ++j) {
        int r0  = wid * 16 + j * 2;
        int row = r0 + rp;
        int sc  = c ^ (row & 7);
        gl_lds16(Ub + (size_t)(nb + row) * RANK + sc * 8, udst + r0 * RANK);
    }
}

__device__ __forceinline__ void g1_pack(float4 a, float4 b, unsigned short* dst) {
    union { bf16x8 v; unsigned short s[8]; } pk;
    pk.s[0] = f2bf(a.x); pk.s[1] = f2bf(a.y);
    pk.s[2] = f2bf(a.z); pk.s[3] = f2bf(a.w);
    pk.s[4] = f2bf(b.x); pk.s[5] = f2bf(b.y);
    pk.s[6] = f2bf(b.z); pk.s[7] = f2bf(b.w);
    *(bf16x8*)dst = pk.v;
}

__device__ __forceinline__ void g1_compute(f32x4 (&acc)[2][2],
                                           const unsigned short* vbuf,
                                           const unsigned short* abuf,
                                           int l15, int quad, int wid) {
    const int rr0 = wid * 32 + l15;
    const int sw  = l15 & 7;
    #pragma unroll
    for (int ks = 0; ks < 4; ++ks) {
        int p = ((ks * 4 + quad) ^ sw) * 8;
        bf16x8 v0 = *(const bf16x8*)&vbuf[rr0 * BK + p];
        bf16x8 v1 = *(const bf16x8*)&vbuf[(rr0 + 16) * BK + p];
        bf16x8 b0 = *(const bf16x8*)&abuf[l15 * ASTR + ks * 32 + quad * 8];
        bf16x8 b1 = *(const bf16x8*)&abuf[(16 + l15) * ASTR + ks * 32 + quad * 8];
        acc[0][0] = __builtin_amdgcn_mfma_f32_16x16x32_bf16(v0, b0, acc[0][0], 0, 0, 0);
        acc[0][1] = __builtin_amdgcn_mfma_f32_16x16x32_bf16(v0, b1, acc[0][1], 0, 0, 0);
        acc[1][0] = __builtin_amdgcn_mfma_f32_16x16x32_bf16(v1, b0, acc[1][0], 0, 0, 0);
        acc[1][1] = __builtin_amdgcn_mfma_f32_16x16x32_bf16(v1, b1, acc[1][1], 0, 0, 0);
    }
}

__device__ __forceinline__ void p2_body(const bf16x8 (&tf)[8][2],
                                        const unsigned short* ubuf,
                                        float* __restrict__ out,
                                        const float* __restrict__ bias,
                                        int m0, int nb, int wid, int l15, int quad) {
    f32x4 a0 = (f32x4){0.f, 0.f, 0.f, 0.f};
    f32x4 a1 = (f32x4){0.f, 0.f, 0.f, 0.f};
    const int ub = (wid * 16 + l15) * RANK;
    const int sw = l15 & 7;
    #pragma unroll
    for (int ks = 0; ks < 8; ++ks) {
        bf16x8 uf = *(const bf16x8*)&ubuf[ub + (((ks * 4 + quad) ^ sw) * 8)];
        a0 = __builtin_amdgcn_mfma_f32_16x16x32_bf16(uf, tf[ks][0], a0, 0, 0, 0);
        a1 = __builtin_amdgcn_mfma_f32_16x16x32_bf16(uf, tf[ks][1], a1, 0, 0, 0);
    }
    const int nc = nb + wid * 16 + quad * 4;
    float4 bb = *(const float4*)&bias[nc];
    float4 v0, v1;
    v0.x = a0[0] + bb.x; v0.y = a0[1] + bb.y; v0.z = a0[2] + bb.z; v0.w = a0[3] + bb.w;
    v1.x = a1[0] + bb.x; v1.y = a1[1] + bb.y; v1.z = a1[2] + bb.z; v1.w = a1[3] + bb.w;
    *(float4*)&out[(size_t)(m0 + l15) * OUTF + nc] = v0;
    *(float4*)&out[(size_t)(m0 + 16 + l15) * OUTF + nc] = v1;
}

__global__ __launch_bounds__(512, 2) void fused(const float* __restrict__ x,
                                                const unsigned short* __restrict__ Vb,
                                                const unsigned short* __restrict__ Ub,
                                                const float* __restrict__ bias,
                                                float* __restrict__ out) {
    __shared__ __align__(16) unsigned short SM[SMSZ];

    const int tid  = threadIdx.x;
    const int lane = tid & 63;
    const int wid  = tid >> 6;            // 0..7
    const int m0   = blockIdx.x * BM;
    const int l15  = lane & 15;
    const int quad = lane >> 4;

    // ---------------- phase 1 ----------------
    const int arow = tid >> 4;
    const int aseg = tid & 15;
    const float* xp = x + (size_t)(m0 + arow) * INF + aseg * 8;
    unsigned short* aw0 = &SM[AB0 + arow * ASTR + aseg * 8];
    unsigned short* aw1 = &SM[AB1 + arow * ASTR + aseg * 8];

    f32x4 acc[2][2];
    #pragma unroll
    for (int i = 0; i < 2; ++i)
        #pragma unroll
        for (int j = 0; j < 2; ++j) acc[i][j] = (f32x4){0.f, 0.f, 0.f, 0.f};

    // prologue: V(0)->vb0; x(0) packed to a0; x(1) in regs A
    stageV(Vb, SM + VB0, 0, wid, lane);
    float4 pA0 = *(const float4*)(xp);
    float4 pA1 = *(const float4*)(xp + 4);
    g1_pack(pA0, pA1, aw0);
    pA0 = *(const float4*)(xp + BK);
    pA1 = *(const float4*)(xp + BK + 4);
    float4 pB0, pB1;

    #pragma unroll 1
    for (int t = 0; t < 30; t += 2) {
        __syncthreads();                       // V(t)@vb0, x(t)@a0 ready
        pB0 = *(const float4*)(xp + (t + 2) * BK);        // load B <- x(t+2)
        pB1 = *(const float4*)(xp + (t + 2) * BK + 4);
        stageV(Vb, SM + VB1, (t + 1) * BK, wid, lane);
        g1_compute(acc, SM + VB0, SM + AB0, l15, quad, wid);
        g1_pack(pA0, pA1, aw1);                // x(t+1) -> a1

        __syncthreads();                       // V(t+1)@vb1, x(t+1)@a1 ready
        pA0 = *(const float4*)(xp + (t + 3) * BK);        // load A <- x(t+3)
        pA1 = *(const float4*)(xp + (t + 3) * BK + 4);
        stageV(Vb, SM + VB0, (t + 2) * BK, wid, lane);
        g1_compute(acc, SM + VB1, SM + AB1, l15, quad, wid);
        g1_pack(pB0, pB1, aw0);                // x(t+2) -> a0
    }
    // peeled tiles 30, 31; U(0) staging folded into the last iteration
    __syncthreads();                           // V(30)@vb0, x(30)@a0
    stageV(Vb, SM + VB1, 31 * BK, wid, lane);
    g1_compute(acc, SM + VB0, SM + AB0, l15, quad, wid);   // tile 30
    g1_pack(pA0, pA1, aw1);                    // x(31) -> a1
    __syncthreads();                           // V(31)@vb1, x(31)@a1
    stageU(Ub, SM + VB0, 0, wid, lane);        // U(0) -> vb0 (vb0 free)
    g1_compute(acc, SM + VB1, SM + AB1, l15, quad, wid);   // tile 31
    __syncthreads();                           // phase-1 reads done; U0 drained

    // ---------------- T: acc -> LDS (swizzled), then -> registers ----------
    // acc[mv][mx]: lane holds ranks wid*32+mv*16+quad*4+{0..3} of token mx*16+l15
    #pragma unroll
    for (int mv = 0; mv < 2; ++mv)
        #pragma unroll
        for (int mx = 0; mx < 2; ++mx) {
            int tok = mx * 16 + l15;
            int cc  = wid * 4 + mv * 2 + (quad >> 1);     // 16B chunk of rank
            int sc  = cc ^ (tok & 7);
            ushort4 o;
            o.x = f2bf(acc[mv][mx][0]); o.y = f2bf(acc[mv][mx][1]);
            o.z = f2bf(acc[mv][mx][2]); o.w = f2bf(acc[mv][mx][3]);
            *(ushort4*)&SM[TB0 + tok * RANK + sc * 8 + (quad & 1) * 4] = o;
        }
    __syncthreads();                           // T visible

    bf16x8 tf[8][2];                           // T-frags, loop-invariant
    #pragma unroll
    for (int ks = 0; ks < 8; ++ks)
        #pragma unroll
        for (int mt = 0; mt < 2; ++mt) {
            int tok = mt * 16 + l15;
            tf[ks][mt] = *(const bf16x8*)
                &SM[TB0 + tok * RANK + (((ks * 4 + quad) ^ (l15 & 7)) * 8)];
        }

    // ---------------- phase 2 ----------------
    #pragma unroll 1
    for (int u = 0; u < 32; u += 2) {
        if (u) __syncthreads();                // U(u)@vb0 ready
        stageU(Ub, SM + VB1, (u + 1) * 128, wid, lane);
        p2_body(tf, SM + VB0, out, bias, m0, u * 128, wid, l15, quad);
        __syncthreads();                       // U(u+1)@vb1 ready
        if (u + 2 < 32) stageU(Ub, SM + VB0, (u + 2) * 128, wid, lane);
        p2_body(tf, SM + VB1, out, bias, m0, (u + 1) * 128, wid, l15, quad);
    }
}

extern "C" void kernel_launch(void* const* d_in, const int* in_sizes, int n_in,
                              void* d_out, int out_size, void* d_ws, size_t ws_size,
                              hipStream_t stream) {
    const float* x    = (const float*)d_in[0];
    const float* U    = (const float*)d_in[1];
    const float* V    = (const float*)d_in[2];
    const float* bias = (const float*)d_in[3];
    float* out = (float*)d_out;

    // ws layout: Vb (2MB) | Ub (2MB)
    unsigned short* Vb = (unsigned short*)d_ws;
    unsigned short* Ub = Vb + (size_t)RANK * INF;

    const int nv = RANK * INF / 4;   // float4 elems in V
    const int nu = OUTF * RANK / 4;  // float4 elems in U
    cvt4<<<(nv + nu) / 256, 256, 0, stream>>>((const float4*)V, (ushort4*)Vb, nv,
                                              (const float4*)U, (ushort4*)Ub);
    fused<<<TOKENS / BM, 512, 0, stream>>>(x, Vb, Ub, bias, out);
}